// Round 5
// baseline (845.431 us; speedup 1.0000x reference)
//
#include <hip/hip_runtime.h>
#include <math.h>

// Problem constants (fixed by reference)
#define BS_TOT 32768      // B*S = 16*2048
#define IN_DIM 768
#define G_N 2
#define V_N 320
#define D_N 384
#define OUT_N 768
#define EPS_F 1e-10f

typedef _Float16 f16x8 __attribute__((ext_vector_type(8)));
typedef float    f32x16 __attribute__((ext_vector_type(16)));

#define GLOBAL_LOAD_LDS16(gaddr, laddr)                                        \
  __builtin_amdgcn_global_load_lds(                                            \
      (const __attribute__((address_space(1))) unsigned int*)(gaddr),          \
      (__attribute__((address_space(3))) unsigned int*)(laddr), 16, 0, 0)

// ---------------------------------------------------------------------------
// Kernel 0: split W_logits [384][320] fp32 into two f16 planes, laid out as
// five 96 KB column-chunk panels (validated R2 layout):
//   panel c (cols 64c..64c+63), unit u = ((t*2+plane)*2+kh)*64 + col,
//   k = t*16 + kh*8 + j.  Plane 0 = f16(w); plane 1 = f16(4096*(w-plane0)).
// Also zeroes the 128 per-m-tile completion counters (block 0).
// ---------------------------------------------------------------------------
__global__ __launch_bounds__(256) void prep_w(
    const float* __restrict__ Wl, _Float16* __restrict__ Wp,
    int* __restrict__ ctr)
{
    if (blockIdx.x == 0 && threadIdx.x < 128) ctr[threadIdx.x] = 0;
    int e = blockIdx.x * 256 + threadIdx.x;
    if (e >= D_N * V_N) return;
    int k = e / V_N, v = e - k * V_N;
    int c = v >> 6, col = v & 63;
    int t = k >> 4, kh = (k >> 3) & 1, j = k & 7;
    float w = Wl[e];
    _Float16 a = (_Float16)w;
    float r = (w - (float)a) * 4096.f;
    size_t u0 = (size_t)c * 6144 + ((t * 2 + 0) * 2 + kh) * 64 + col;
    size_t u1 = (size_t)c * 6144 + ((t * 2 + 1) * 2 + kh) * 64 + col;
    Wp[u0 * 8 + j] = a;
    Wp[u1 * 8 + j] = (_Float16)r;
}

// ---------------------------------------------------------------------------
// Kernel A: P[g*320+v][o] = sum_d codebooks[g][v][d] * W_out[g*384+d][o]
// (unchanged — validated)
// ---------------------------------------------------------------------------
__global__ __launch_bounds__(256) void precompute_P(
    const float* __restrict__ cb, const float* __restrict__ Wo,
    float* __restrict__ P)
{
    const int tid = threadIdx.x;
    const int c0  = blockIdx.x * 256;
    const int r0  = blockIdx.y * 8;
    const int g   = r0 / V_N;
    __shared__ float As[8][D_N];
    {
        const float4* src = (const float4*)(cb + (size_t)r0 * D_N);
        float4* dst = (float4*)(&As[0][0]);
        #pragma unroll
        for (int p = 0; p < 3; ++p) dst[tid + p * 256] = src[tid + p * 256];
    }
    __syncthreads();
    float acc[8];
    #pragma unroll
    for (int i = 0; i < 8; ++i) acc[i] = 0.f;
    const float* wp = Wo + ((size_t)g * D_N) * OUT_N + c0 + tid;
    for (int d = 0; d < D_N; d += 4) {
        float w0 = wp[(size_t)(d + 0) * OUT_N];
        float w1 = wp[(size_t)(d + 1) * OUT_N];
        float w2 = wp[(size_t)(d + 2) * OUT_N];
        float w3 = wp[(size_t)(d + 3) * OUT_N];
        #pragma unroll
        for (int i = 0; i < 8; ++i) {
            float4 a = *(const float4*)&As[i][d];
            acc[i] = fmaf(a.x, w0, acc[i]);
            acc[i] = fmaf(a.y, w1, acc[i]);
            acc[i] = fmaf(a.z, w2, acc[i]);
            acc[i] = fmaf(a.w, w3, acc[i]);
        }
    }
    #pragma unroll
    for (int i = 0; i < 8; ++i)
        P[(size_t)(r0 + i) * OUT_N + c0 + tid] = acc[i];
}

// ---------------------------------------------------------------------------
// Kernel B: logits GEMM + gumbel + per-chunk argmax + fused last-block finish.
// Identical validated main loop (48 KB ring, 8 waves, 32x64 wave tile, 4
// barriers). NEW: (1) XCD swizzle — 1D grid, j = xcd + 8*(mtq*10+sub), so all
// 10 (cc,g) blocks of an m-tile run on ONE XCD -> z re-reads hit that XCD's
// L2 (~200cy) instead of L3/HBM (~600-900cy). (2) last-of-10 block (device-
// scope atomic + fences) combines the 5 chunk partials (ascending-chunk
// strict-> == first-max == jnp.argmax) and writes out = P[i0]+P[320+i1]+bo.
// ---------------------------------------------------------------------------
__global__ __launch_bounds__(512, 4) void logits_part(
    const float* __restrict__ z, const float* __restrict__ noise,
    const f16x8* __restrict__ Wp, const float* __restrict__ bl,
    float* __restrict__ pv, int* __restrict__ pi,
    int* __restrict__ ctr, const float* __restrict__ P,
    const float* __restrict__ bo, float* __restrict__ out)
{
    const int tid = threadIdx.x;
    const int ln  = tid & 63;
    const int wv  = tid >> 6;          // 0..7
    const int lh  = ln >> 5;
    const int l5  = ln & 31;
    // XCD swizzle: co-m-tile blocks -> same XCD
    const int j    = blockIdx.x;       // 0..1279
    const int xcd  = j & 7;
    const int slot = j >> 3;           // 0..159
    const int mtq  = slot / 10;
    const int sub  = slot - mtq * 10;
    const int mt   = mtq * 8 + xcd;    // 0..127
    const int cc   = sub % 5;          // N-chunk
    const int g    = sub / 5;          // group
    const int m0   = mt * 256;         // M-tile base

    __shared__ f16x8 Bs[3072];         // 49152 B ring: 2 slots x 1536 units

    const f16x8* wsrc = Wp + (size_t)cc * 6144;

#define STAGEQ(Q, SLOT)                                                        \
    {                                                                          \
        _Pragma("unroll")                                                      \
        for (int i_ = 0; i_ < 3; ++i_)                                         \
            GLOBAL_LOAD_LDS16(wsrc + (Q) * 1536 + i_ * 512 + wv * 64 + ln,     \
                              Bs + (SLOT) * 1536 + i_ * 512 + wv * 64);        \
    }

    // prologue: stage Q0 -> slot0, Q1 -> slot1
    STAGEQ(0, 0)
    STAGEQ(1, 1)

    // z: lane's A fragment addr: row = m0 + wv*32 + l5, k = t*16 + lh*8 + j
    const float* zb = z + (size_t)(m0 + wv * 32 + l5) * IN_DIM + g * D_N + lh * 8;
    float4 pa0 = *(const float4*)(zb);        // t=0
    float4 pa1 = *(const float4*)(zb + 4);
    float4 pb0 = *(const float4*)(zb + 16);   // t=1
    float4 pb1 = *(const float4*)(zb + 20);

    f32x16 aM0, aM1, aC0, aC1;
    #pragma unroll
    for (int i = 0; i < 16; ++i) { aM0[i] = 0.f; aM1[i] = 0.f; aC0[i] = 0.f; aC1[i] = 0.f; }

    __syncthreads();   // Q0,Q1 resident

#define STEP(T, SLOT, P0, P1)                                                  \
    {                                                                          \
        float x_[8] = {P0.x, P0.y, P0.z, P0.w, P1.x, P1.y, P1.z, P1.w};        \
        f16x8 h1, h2;                                                          \
        _Pragma("unroll")                                                      \
        for (int i_ = 0; i_ < 8; ++i_) {                                       \
            _Float16 a_ = (_Float16)x_[i_];                                    \
            h1[i_] = a_;                                                       \
            h2[i_] = (_Float16)((x_[i_] - (float)a_) * 4096.f);                \
        }                                                                      \
        if ((T) + 2 < 24) {                                                    \
            P0 = *(const float4*)(zb + ((T) + 2) * 16);                        \
            P1 = *(const float4*)(zb + ((T) + 2) * 16 + 4);                    \
        }                                                                      \
        const int tq2_ = ((T) % 6) * 2;                                        \
        f16x8 Bm0 = Bs[(SLOT) * 1536 + ((tq2_ + 0) * 2 + lh) * 64 + l5];       \
        f16x8 Bc0 = Bs[(SLOT) * 1536 + ((tq2_ + 1) * 2 + lh) * 64 + l5];       \
        f16x8 Bm1 = Bs[(SLOT) * 1536 + ((tq2_ + 0) * 2 + lh) * 64 + 32 + l5];  \
        f16x8 Bc1 = Bs[(SLOT) * 1536 + ((tq2_ + 1) * 2 + lh) * 64 + 32 + l5];  \
        aM0 = __builtin_amdgcn_mfma_f32_32x32x16_f16(h1, Bm0, aM0, 0, 0, 0);   \
        aC0 = __builtin_amdgcn_mfma_f32_32x32x16_f16(h1, Bc0, aC0, 0, 0, 0);   \
        aC0 = __builtin_amdgcn_mfma_f32_32x32x16_f16(h2, Bm0, aC0, 0, 0, 0);   \
        aM1 = __builtin_amdgcn_mfma_f32_32x32x16_f16(h1, Bm1, aM1, 0, 0, 0);   \
        aC1 = __builtin_amdgcn_mfma_f32_32x32x16_f16(h1, Bc1, aC1, 0, 0, 0);   \
        aC1 = __builtin_amdgcn_mfma_f32_32x32x16_f16(h2, Bm1, aC1, 0, 0, 0);   \
    }

    STEP(0, 0, pa0, pa1) STEP(1, 0, pb0, pb1) STEP(2, 0, pa0, pa1)
    STEP(3, 0, pb0, pb1) STEP(4, 0, pa0, pa1) STEP(5, 0, pb0, pb1)
    __syncthreads();           // slot0 free (all waves past t=5)
    STAGEQ(2, 0)               // in flight across next 6 steps
    STEP(6, 1, pa0, pa1) STEP(7, 1, pb0, pb1) STEP(8, 1, pa0, pa1)
    STEP(9, 1, pb0, pb1) STEP(10, 1, pa0, pa1) STEP(11, 1, pb0, pb1)
    __syncthreads();           // drains Q2 DMA; slot1 free
    STAGEQ(3, 1)
    STEP(12, 0, pa0, pa1) STEP(13, 0, pb0, pb1) STEP(14, 0, pa0, pa1)
    STEP(15, 0, pb0, pb1) STEP(16, 0, pa0, pa1) STEP(17, 0, pb0, pb1)
    __syncthreads();           // drains Q3 DMA
    STEP(18, 1, pa0, pa1) STEP(19, 1, pb0, pb1) STEP(20, 1, pa0, pa1)
    STEP(21, 1, pb0, pb1) STEP(22, 1, pa0, pa1) STEP(23, 1, pb0, pb1)

#undef STEP
#undef STAGEQ

    // ---- epilogue: logits = main + 2^-12*cross + bl + gumbel; chunk argmax -
    const float blv0 = bl[cc * 64 + l5];
    const float blv1 = bl[cc * 64 + 32 + l5];
    const int   col0 = cc * 64 + l5;
    const int   col1 = cc * 64 + 32 + l5;

    #pragma unroll
    for (int r = 0; r < 16; ++r) {
        const int rowloc = (r & 3) + 8 * (r >> 2) + 4 * lh;   // C/D row map
        const int grow   = m0 + wv * 32 + rowloc;
        const float* np_ = noise + ((size_t)grow * G_N + g) * V_N + cc * 64 + l5;
        float u0 = np_[0];
        float u1 = np_[32];
        float g0 = -__logf(-__logf(u0 + EPS_F) + EPS_F);
        float g1 = -__logf(-__logf(u1 + EPS_F) + EPS_F);
        float v0 = aM0[r] + 2.44140625e-4f * aC0[r] + blv0 + g0;
        float v1 = aM1[r] + 2.44140625e-4f * aC1[r] + blv1 + g1;
        float best = v0; int bi = col0;
        if (v1 > best) { best = v1; bi = col1; }
        #pragma unroll
        for (int off = 1; off < 32; off <<= 1) {   // reduce within 32-lane half
            float ov = __shfl_xor(best, off);
            int   oi = __shfl_xor(bi, off);
            if (ov > best || (ov == best && oi < bi)) { best = ov; bi = oi; }
        }
        if (l5 == 0) {
            pv[(size_t)(g * 5 + cc) * BS_TOT + grow] = best;
            pi[(size_t)(g * 5 + cc) * BS_TOT + grow] = bi;
        }
    }

    // ---- fused finish: last of the 10 co-m-tile blocks gathers + writes ----
    __threadfence();                       // release pv/pi stores (device scope)
    __syncthreads();                       // all threads' fences done
    int* sW   = (int*)&Bs[0];              // reuse dead ring: 512 winners + flag
    if (tid == 0) sW[512] = (atomicAdd(&ctr[mt], 1) == 9) ? 1 : 0;
    __syncthreads();
    if (sW[512] == 0) return;              // uniform per block
    __threadfence();                       // acquire: see all 10 blocks' pv/pi

    // combine 5 chunks per (row, group): tid -> row = tid>>1, gg = tid&1
    {
        const int row = tid >> 1;
        const int gg  = tid & 1;
        const float* pvb = pv + (size_t)gg * 5 * BS_TOT + (m0 + row);
        const int*   pib = pi + (size_t)gg * 5 * BS_TOT + (m0 + row);
        float best = pvb[0];
        int   bi   = pib[0];
        #pragma unroll
        for (int c = 1; c < 5; ++c) {
            float v = pvb[(size_t)c * BS_TOT];
            int   i = pib[(size_t)c * BS_TOT];
            if (v > best) { best = v; bi = i; }
        }
        sW[gg * 256 + row] = bi;
    }
    __syncthreads();

    // gather: out[m0+rl] = P[i0] + P[320+i1] + bo   (256 rows x 192 float4)
    {
        const float4* Pv  = (const float4*)P;
        const float4* bov = (const float4*)bo;
        #pragma unroll 4
        for (int p = 0; p < 96; ++p) {
            int f  = p * 512 + tid;        // 49152 slots
            int rl = f / 192;
            int c4 = f - rl * 192;
            int i0 = sW[rl];
            int i1 = sW[256 + rl];
            float4 a  = Pv[(size_t)i0 * 192 + c4];
            float4 b2 = Pv[(size_t)(V_N + i1) * 192 + c4];
            float4 c  = bov[c4];
            float4 r;
            r.x = a.x + b2.x + c.x;
            r.y = a.y + b2.y + c.y;
            r.z = a.z + b2.z + c.z;
            r.w = a.w + b2.w + c.w;
            ((float4*)(out + (size_t)(m0 + rl) * OUT_N))[c4] = r;
        }
    }
}

// ---------------------------------------------------------------------------
extern "C" void kernel_launch(void* const* d_in, const int* in_sizes, int n_in,
                              void* d_out, int out_size, void* d_ws, size_t ws_size,
                              hipStream_t stream)
{
    const float* z     = (const float*)d_in[0];
    const float* noise = (const float*)d_in[1];
    const float* Wl    = (const float*)d_in[2];
    const float* bl    = (const float*)d_in[3];
    const float* cb    = (const float*)d_in[4];
    const float* Wo    = (const float*)d_in[5];
    const float* bo    = (const float*)d_in[6];
    float* out = (float*)d_out;

    // ws: P (1,966,080) | pv (1,310,720) | pi (1,310,720) | Wp (491,520) | ctr (512)
    float*     P   = (float*)d_ws;
    float*     pv  = (float*)((char*)d_ws + 1966080);
    int*       pi  = (int*)((char*)d_ws + 3276800);
    _Float16*  Wp  = (_Float16*)((char*)d_ws + 4587520);
    int*       ctr = (int*)((char*)d_ws + 5079040);

    prep_w<<<(D_N * V_N + 255) / 256, 256, 0, stream>>>(Wl, Wp, ctr);

    dim3 gA(OUT_N / 256, (G_N * V_N) / 8);
    precompute_P<<<gA, 256, 0, stream>>>(cb, Wo, P);

    logits_part<<<1280, 512, 0, stream>>>(
        z, noise, (const f16x8*)Wp, bl, pv, pi, ctr, P, bo, out);
}

// Round 6
// 391.783 us; speedup vs baseline: 2.1579x; 2.1579x over previous
//
#include <hip/hip_runtime.h>
#include <math.h>

// Problem constants (fixed by reference)
#define BS_TOT 32768      // B*S = 16*2048
#define IN_DIM 768
#define G_N 2
#define V_N 320
#define D_N 384
#define OUT_N 768
#define EPS_F 1e-10f

typedef _Float16 f16x8 __attribute__((ext_vector_type(8)));
typedef float    f32x16 __attribute__((ext_vector_type(16)));

#define GLOBAL_LOAD_LDS16(gaddr, laddr)                                        \
  __builtin_amdgcn_global_load_lds(                                            \
      (const __attribute__((address_space(1))) unsigned int*)(gaddr),          \
      (__attribute__((address_space(3))) unsigned int*)(laddr), 16, 0, 0)

// ---------------------------------------------------------------------------
// Kernel 0: split W_logits [384][320] fp32 into two f16 planes, laid out as
// five 96 KB column-chunk panels (validated R2 layout):
//   panel c (cols 64c..64c+63), unit u = ((t*2+plane)*2+kh)*64 + col,
//   k = t*16 + kh*8 + j.  Plane 0 = f16(w); plane 1 = f16(4096*(w-plane0)).
// ---------------------------------------------------------------------------
__global__ __launch_bounds__(256) void prep_w(
    const float* __restrict__ Wl, _Float16* __restrict__ Wp)
{
    int e = blockIdx.x * 256 + threadIdx.x;
    if (e >= D_N * V_N) return;
    int k = e / V_N, v = e - k * V_N;
    int c = v >> 6, col = v & 63;
    int t = k >> 4, kh = (k >> 3) & 1, j = k & 7;
    float w = Wl[e];
    _Float16 a = (_Float16)w;
    float r = (w - (float)a) * 4096.f;
    size_t u0 = (size_t)c * 6144 + ((t * 2 + 0) * 2 + kh) * 64 + col;
    size_t u1 = (size_t)c * 6144 + ((t * 2 + 1) * 2 + kh) * 64 + col;
    Wp[u0 * 8 + j] = a;
    Wp[u1 * 8 + j] = (_Float16)r;
}

// ---------------------------------------------------------------------------
// Kernel 0b: pre-split z into two interleaved f16 planes. Element-group e
// (8 consecutive floats of row-major z) -> zsp[e*2] = hi, zsp[e*2+1] = lo.
// Removes the 5x-redundant per-step conversion chain from the main loop.
// ---------------------------------------------------------------------------
__global__ __launch_bounds__(256) void prep_z(
    const float* __restrict__ z, f16x8* __restrict__ zsp)
{
    int e = blockIdx.x * 256 + threadIdx.x;   // e < 32768*96 = 3,145,728 exact
    const float4* src = (const float4*)z;
    float4 q0 = src[(size_t)e * 2];
    float4 q1 = src[(size_t)e * 2 + 1];
    float x[8] = {q0.x, q0.y, q0.z, q0.w, q1.x, q1.y, q1.z, q1.w};
    f16x8 h1, h2;
    #pragma unroll
    for (int i = 0; i < 8; ++i) {
        _Float16 a = (_Float16)x[i];
        h1[i] = a;
        h2[i] = (_Float16)((x[i] - (float)a) * 4096.f);
    }
    zsp[(size_t)e * 2]     = h1;
    zsp[(size_t)e * 2 + 1] = h2;
}

// ---------------------------------------------------------------------------
// Kernel A: P[g*320+v][o] = sum_d codebooks[g][v][d] * W_out[g*384+d][o]
// (unchanged — validated)
// ---------------------------------------------------------------------------
__global__ __launch_bounds__(256) void precompute_P(
    const float* __restrict__ cb, const float* __restrict__ Wo,
    float* __restrict__ P)
{
    const int tid = threadIdx.x;
    const int c0  = blockIdx.x * 256;
    const int r0  = blockIdx.y * 8;
    const int g   = r0 / V_N;
    __shared__ float As[8][D_N];
    {
        const float4* src = (const float4*)(cb + (size_t)r0 * D_N);
        float4* dst = (float4*)(&As[0][0]);
        #pragma unroll
        for (int p = 0; p < 3; ++p) dst[tid + p * 256] = src[tid + p * 256];
    }
    __syncthreads();
    float acc[8];
    #pragma unroll
    for (int i = 0; i < 8; ++i) acc[i] = 0.f;
    const float* wp = Wo + ((size_t)g * D_N) * OUT_N + c0 + tid;
    for (int d = 0; d < D_N; d += 4) {
        float w0 = wp[(size_t)(d + 0) * OUT_N];
        float w1 = wp[(size_t)(d + 1) * OUT_N];
        float w2 = wp[(size_t)(d + 2) * OUT_N];
        float w3 = wp[(size_t)(d + 3) * OUT_N];
        #pragma unroll
        for (int i = 0; i < 8; ++i) {
            float4 a = *(const float4*)&As[i][d];
            acc[i] = fmaf(a.x, w0, acc[i]);
            acc[i] = fmaf(a.y, w1, acc[i]);
            acc[i] = fmaf(a.z, w2, acc[i]);
            acc[i] = fmaf(a.w, w3, acc[i]);
        }
    }
    #pragma unroll
    for (int i = 0; i < 8; ++i)
        P[(size_t)(r0 + i) * OUT_N + c0 + tid] = acc[i];
}

// ---------------------------------------------------------------------------
// Kernel B: logits GEMM + gumbel + per-chunk argmax. Validated R4 main loop
// (48 KB ring, 8 waves, 32x64 wave tile, 4 barriers) + XCD swizzle (R5,
// proven: FETCH 296->135 MB). R5's device-fence/atomic tail REMOVED (it
// forced per-block L2 writebacks -> 4x regression); finish is a separate
// kernel again. ZSP=1: A fragments come pre-split from zsp (two f16x8 loads,
// zero conversion VALU); ZSP=0 fallback converts in-loop (R4-identical).
// ---------------------------------------------------------------------------
template<int ZSP>
__global__ __launch_bounds__(512, 4) void logits_part(
    const float* __restrict__ z, const f16x8* __restrict__ zsp,
    const float* __restrict__ noise, const f16x8* __restrict__ Wp,
    const float* __restrict__ bl, float* __restrict__ pv, int* __restrict__ pi)
{
    const int tid = threadIdx.x;
    const int ln  = tid & 63;
    const int wv  = tid >> 6;          // 0..7
    const int lh  = ln >> 5;
    const int l5  = ln & 31;
    // XCD swizzle: all 10 (cc,g) blocks of an m-tile land on one XCD
    const int j    = blockIdx.x;       // 0..1279
    const int xcd  = j & 7;
    const int slot = j >> 3;           // 0..159
    const int mtq  = slot / 10;
    const int sub  = slot - mtq * 10;
    const int mt   = mtq * 8 + xcd;    // 0..127
    const int cc   = sub % 5;          // N-chunk
    const int g    = sub / 5;          // group
    const int m0   = mt * 256;         // M-tile base

    __shared__ f16x8 Bs[3072];         // 49152 B ring: 2 slots x 1536 units

    const f16x8* wsrc = Wp + (size_t)cc * 6144;

#define STAGEQ(Q, SLOT)                                                        \
    {                                                                          \
        _Pragma("unroll")                                                      \
        for (int i_ = 0; i_ < 3; ++i_)                                         \
            GLOBAL_LOAD_LDS16(wsrc + (Q) * 1536 + i_ * 512 + wv * 64 + ln,     \
                              Bs + (SLOT) * 1536 + i_ * 512 + wv * 64);        \
    }

    // prologue: stage Q0 -> slot0, Q1 -> slot1
    STAGEQ(0, 0)
    STAGEQ(1, 1)

    // A addressing: row = m0 + wv*32 + l5, k = t*16 + lh*8 + {0..7}
    const float* zb   = z + (size_t)(m0 + wv * 32 + l5) * IN_DIM + g * D_N + lh * 8;
    const f16x8* zrow = zsp + ((size_t)(m0 + wv * 32 + l5) * 96 + g * 48 + lh) * 2;

    // prefetch depth 2 (statically-named buffers; unused set is DCE'd)
    f16x8  paH = {}, paL = {}, pbH = {}, pbL = {};
    float4 fa0 = {}, fa1 = {}, fb0 = {}, fb1 = {};
    if (ZSP) {
        paH = zrow[0]; paL = zrow[1];          // t=0
        pbH = zrow[4]; pbL = zrow[5];          // t=1
    } else {
        fa0 = *(const float4*)(zb);            // t=0
        fa1 = *(const float4*)(zb + 4);
        fb0 = *(const float4*)(zb + 16);       // t=1
        fb1 = *(const float4*)(zb + 20);
    }

    f32x16 aM0, aM1, aC0, aC1;
    #pragma unroll
    for (int i = 0; i < 16; ++i) { aM0[i] = 0.f; aM1[i] = 0.f; aC0[i] = 0.f; aC1[i] = 0.f; }

    __syncthreads();   // Q0,Q1 resident

#define STEP(T, SLOT, PH, PL, F0, F1)                                          \
    {                                                                          \
        f16x8 h1, h2;                                                          \
        if (ZSP) {                                                             \
            h1 = PH; h2 = PL;                                                  \
            if ((T) + 2 < 24) {                                                \
                PH = zrow[((T) + 2) * 4];                                      \
                PL = zrow[((T) + 2) * 4 + 1];                                  \
            }                                                                  \
        } else {                                                               \
            float x_[8] = {F0.x, F0.y, F0.z, F0.w, F1.x, F1.y, F1.z, F1.w};    \
            _Pragma("unroll")                                                  \
            for (int i_ = 0; i_ < 8; ++i_) {                                   \
                _Float16 a_ = (_Float16)x_[i_];                                \
                h1[i_] = a_;                                                   \
                h2[i_] = (_Float16)((x_[i_] - (float)a_) * 4096.f);            \
            }                                                                  \
            if ((T) + 2 < 24) {                                                \
                F0 = *(const float4*)(zb + ((T) + 2) * 16);                    \
                F1 = *(const float4*)(zb + ((T) + 2) * 16 + 4);                \
            }                                                                  \
        }                                                                      \
        const int tq2_ = ((T) % 6) * 2;                                        \
        f16x8 Bm0 = Bs[(SLOT) * 1536 + ((tq2_ + 0) * 2 + lh) * 64 + l5];       \
        f16x8 Bc0 = Bs[(SLOT) * 1536 + ((tq2_ + 1) * 2 + lh) * 64 + l5];       \
        f16x8 Bm1 = Bs[(SLOT) * 1536 + ((tq2_ + 0) * 2 + lh) * 64 + 32 + l5];  \
        f16x8 Bc1 = Bs[(SLOT) * 1536 + ((tq2_ + 1) * 2 + lh) * 64 + 32 + l5];  \
        aM0 = __builtin_amdgcn_mfma_f32_32x32x16_f16(h1, Bm0, aM0, 0, 0, 0);   \
        aC0 = __builtin_amdgcn_mfma_f32_32x32x16_f16(h1, Bc0, aC0, 0, 0, 0);   \
        aC0 = __builtin_amdgcn_mfma_f32_32x32x16_f16(h2, Bm0, aC0, 0, 0, 0);   \
        aM1 = __builtin_amdgcn_mfma_f32_32x32x16_f16(h1, Bm1, aM1, 0, 0, 0);   \
        aC1 = __builtin_amdgcn_mfma_f32_32x32x16_f16(h1, Bc1, aC1, 0, 0, 0);   \
        aC1 = __builtin_amdgcn_mfma_f32_32x32x16_f16(h2, Bm1, aC1, 0, 0, 0);   \
    }

    STEP(0, 0, paH, paL, fa0, fa1) STEP(1, 0, pbH, pbL, fb0, fb1)
    STEP(2, 0, paH, paL, fa0, fa1) STEP(3, 0, pbH, pbL, fb0, fb1)
    STEP(4, 0, paH, paL, fa0, fa1) STEP(5, 0, pbH, pbL, fb0, fb1)
    __syncthreads();           // slot0 free (all waves past t=5)
    STAGEQ(2, 0)               // in flight across next 6 steps
    STEP(6, 1, paH, paL, fa0, fa1) STEP(7, 1, pbH, pbL, fb0, fb1)
    STEP(8, 1, paH, paL, fa0, fa1) STEP(9, 1, pbH, pbL, fb0, fb1)
    STEP(10, 1, paH, paL, fa0, fa1) STEP(11, 1, pbH, pbL, fb0, fb1)
    __syncthreads();           // drains Q2 DMA; slot1 free
    STAGEQ(3, 1)
    STEP(12, 0, paH, paL, fa0, fa1) STEP(13, 0, pbH, pbL, fb0, fb1)
    STEP(14, 0, paH, paL, fa0, fa1) STEP(15, 0, pbH, pbL, fb0, fb1)
    STEP(16, 0, paH, paL, fa0, fa1) STEP(17, 0, pbH, pbL, fb0, fb1)
    __syncthreads();           // drains Q3 DMA
    STEP(18, 1, paH, paL, fa0, fa1) STEP(19, 1, pbH, pbL, fb0, fb1)
    STEP(20, 1, paH, paL, fa0, fa1) STEP(21, 1, pbH, pbL, fb0, fb1)
    STEP(22, 1, paH, paL, fa0, fa1) STEP(23, 1, pbH, pbL, fb0, fb1)

#undef STEP
#undef STAGEQ

    // ---- epilogue: logits = main + 2^-12*cross + bl + gumbel; chunk argmax -
    const float blv0 = bl[cc * 64 + l5];
    const float blv1 = bl[cc * 64 + 32 + l5];
    const int   col0 = cc * 64 + l5;
    const int   col1 = cc * 64 + 32 + l5;

    #pragma unroll
    for (int r = 0; r < 16; ++r) {
        const int rowloc = (r & 3) + 8 * (r >> 2) + 4 * lh;   // C/D row map
        const int grow   = m0 + wv * 32 + rowloc;
        const float* np_ = noise + ((size_t)grow * G_N + g) * V_N + cc * 64 + l5;
        float u0 = np_[0];
        float u1 = np_[32];
        float g0 = -__logf(-__logf(u0 + EPS_F) + EPS_F);
        float g1 = -__logf(-__logf(u1 + EPS_F) + EPS_F);
        float v0 = aM0[r] + 2.44140625e-4f * aC0[r] + blv0 + g0;
        float v1 = aM1[r] + 2.44140625e-4f * aC1[r] + blv1 + g1;
        float best = v0; int bi = col0;
        if (v1 > best) { best = v1; bi = col1; }
        #pragma unroll
        for (int off = 1; off < 32; off <<= 1) {   // reduce within 32-lane half
            float ov = __shfl_xor(best, off);
            int   oi = __shfl_xor(bi, off);
            if (ov > best || (ov == best && oi < bi)) { best = ov; bi = oi; }
        }
        if (l5 == 0) {
            pv[(size_t)(g * 5 + cc) * BS_TOT + grow] = best;
            pi[(size_t)(g * 5 + cc) * BS_TOT + grow] = bi;
        }
    }
}

// ---------------------------------------------------------------------------
// Kernel B2: combine the 5 chunk-partials per (row, group) (strict > with
// ascending chunk == first-max == jnp.argmax semantics), then fused gather:
// out[row] = P[i0] + P[320+i1] + b_out. (unchanged — validated)
// ---------------------------------------------------------------------------
__global__ __launch_bounds__(256) void finish_gather(
    const float* __restrict__ P, const float* __restrict__ pv,
    const int* __restrict__ pi, const float* __restrict__ bo,
    float* __restrict__ out)
{
    const int tid  = threadIdx.x;
    const int row0 = blockIdx.x << 2;
    __shared__ int sI[2][4];
    if (tid < 8) {
        const int gg  = tid >> 2, rl = tid & 3;
        const int row = row0 + rl;
        const float* pvb = pv + (size_t)gg * 5 * BS_TOT + row;
        const int*   pib = pi + (size_t)gg * 5 * BS_TOT + row;
        float best = pvb[0];
        int   bi   = pib[0];
        #pragma unroll
        for (int c = 1; c < 5; ++c) {
            float v = pvb[(size_t)c * BS_TOT];
            int   i = pib[(size_t)c * BS_TOT];
            if (v > best) { best = v; bi = i; }
        }
        sI[gg][rl] = bi;
    }
    __syncthreads();
    const float4* Pv  = (const float4*)P;
    const float4* bov = (const float4*)bo;
    #pragma unroll
    for (int p = 0; p < 3; ++p) {
        int f   = tid + (p << 8);
        int rl  = f / 192;
        int c4  = f - rl * 192;
        int i0  = sI[0][rl];
        int i1  = sI[1][rl];
        float4 a  = Pv[(size_t)i0 * 192 + c4];
        float4 b2 = Pv[(size_t)(V_N + i1) * 192 + c4];
        float4 c  = bov[c4];
        float4 r;
        r.x = a.x + b2.x + c.x;
        r.y = a.y + b2.y + c.y;
        r.z = a.z + b2.z + c.z;
        r.w = a.w + b2.w + c.w;
        ((float4*)(out + (size_t)(row0 + rl) * OUT_N))[c4] = r;
    }
}

// ---------------------------------------------------------------------------
extern "C" void kernel_launch(void* const* d_in, const int* in_sizes, int n_in,
                              void* d_out, int out_size, void* d_ws, size_t ws_size,
                              hipStream_t stream)
{
    const float* z     = (const float*)d_in[0];
    const float* noise = (const float*)d_in[1];
    const float* Wl    = (const float*)d_in[2];
    const float* bl    = (const float*)d_in[3];
    const float* cb    = (const float*)d_in[4];
    const float* Wo    = (const float*)d_in[5];
    const float* bo    = (const float*)d_in[6];
    float* out = (float*)d_out;

    // ws: P (1,966,080) | pv (1,310,720) | pi (1,310,720) | Wp (491,520)
    //     | zsp (100,663,296 — optional, if workspace is large enough)
    float*     P   = (float*)d_ws;
    float*     pv  = (float*)((char*)d_ws + 1966080);
    int*       pi  = (int*)((char*)d_ws + 3276800);
    _Float16*  Wp  = (_Float16*)((char*)d_ws + 4587520);
    f16x8*     zsp = (f16x8*)((char*)d_ws + 5079040);
    const bool use_zsp = ws_size >= (size_t)5079040 + 100663296ull;

    prep_w<<<(D_N * V_N + 255) / 256, 256, 0, stream>>>(Wl, Wp);

    dim3 gA(OUT_N / 256, (G_N * V_N) / 8);
    precompute_P<<<gA, 256, 0, stream>>>(cb, Wo, P);

    if (use_zsp) {
        prep_z<<<(BS_TOT * 96) / 256, 256, 0, stream>>>(z, zsp);
        logits_part<1><<<1280, 512, 0, stream>>>(
            z, zsp, noise, (const f16x8*)Wp, bl, pv, pi);
    } else {
        logits_part<0><<<1280, 512, 0, stream>>>(
            z, zsp, noise, (const f16x8*)Wp, bl, pv, pi);
    }

    finish_gather<<<BS_TOT / 4, 256, 0, stream>>>(P, pv, pi, bo, out);
}